// Round 5
// baseline (74.793 us; speedup 1.0000x reference)
//
#include <hip/hip_runtime.h>
#include <stdint.h>

#define A_CNT 16320
#define N_TOT (23 * A_CNT)       // 375360 windowed anchors per batch
#define G1_END A_CNT             // group0: td=16, W=1
#define G2_END (10 * A_CNT)      // group1: td=8,  W=9
#define BATCH 2
#define TOPK 2000
#define NBIN 2048                // 11-bit histogram of key top bits
#define NREP 4                   // replicated global histograms
#define CANDCAP 4096
#define LCAP 256                 // per-block LDS candidate cap (per batch)
#define TOT4 375360              // total float4 loads (= BATCH*N_TOT/2)
#define INIT_U4 4100             // 65600 bytes / 16
#define HIST_BLOCKS 128

// ws layout:
//   u32[0..1]     T[2] threshold keys
//   u32[2..3]     gCandCnt[2]
//   u32[4]        done counter (last-block detection in k_histscan)
//   byte 64       hist replicas: NREP x [2][NBIN] u32 (64 KB)
//   byte 65600    cand[2][CANDCAP] u64 (64 KB)
// total ~128 KB

__device__ __forceinline__ uint32_t fkey(float v) {
  uint32_t u = __float_as_uint(v);
  return (u & 0x80000000u) ? ~u : (u | 0x80000000u);
}

__global__ void k_init(uint4* ws4) {
  int g = blockIdx.x * blockDim.x + threadIdx.x;
  if (g < INIT_U4) ws4[g] = make_uint4(0u, 0u, 0u, 0u);
}

// g in [0, TOT4): one float4 = scores for anchors (n0, n0+1), batch b.
__device__ __forceinline__ float4 load_pair(int g, const float* __restrict__ s1,
                                            const float* __restrict__ s2,
                                            const float* __restrict__ s3,
                                            int& b, int& n0) {
  if (g < 16320) {                       // s1: [B][1][A][2]
    b = g / 8160;
    int w = g - b * 8160;
    n0 = 2 * w;
    return ((const float4*)s1)[g];
  } else if (g < 163200) {               // s2: [B][9][A][2]
    int h = g - 16320;
    b = h / 73440;
    int w = h - b * 73440;
    int j = w / 8160;
    int p = w - j * 8160;
    n0 = A_CNT + j * A_CNT + 2 * p;
    return ((const float4*)s2)[h];
  } else {                               // s3: [B][13][A][2]
    int h = g - 163200;
    b = h / 106080;
    int w = h - b * 106080;
    int j = w / 8160;
    int p = w - j * 8160;
    n0 = 10 * A_CNT + j * A_CNT + 2 * p;
    return ((const float4*)s3)[h];
  }
}

// Histogram + (in the last-arriving block) threshold scan, fused.
__global__ void __launch_bounds__(256) k_histscan(const float* __restrict__ s1,
                                                  const float* __restrict__ s2,
                                                  const float* __restrict__ s3,
                                                  uint32_t* ws) {
  __shared__ uint32_t lh[BATCH * NBIN];   // 16 KB
  __shared__ uint32_t ps[256];
  __shared__ uint32_t isLast;
  const int tid = threadIdx.x;
  for (int i = tid; i < BATCH * NBIN; i += 256) lh[i] = 0;
  __syncthreads();
  for (int g = blockIdx.x * 256 + tid; g < TOT4; g += gridDim.x * 256) {
    int b, n0;
    float4 v = load_pair(g, s1, s2, s3, b, n0);
    atomicAdd(&lh[b * NBIN + (fkey(v.y) >> 21)], 1u);
    atomicAdd(&lh[b * NBIN + (fkey(v.w) >> 21)], 1u);
  }
  __syncthreads();
  uint32_t* gh = ws + 16 + (blockIdx.x & (NREP - 1)) * (BATCH * NBIN);
  for (int i = tid; i < BATCH * NBIN; i += 256)
    if (lh[i]) atomicAdd(&gh[i], lh[i]);
  __threadfence();
  if (tid == 0) isLast = (atomicAdd(&ws[4], 1u) == (uint32_t)gridDim.x - 1u);
  __syncthreads();
  if (!isLast) return;

  // ---- last block: compute per-batch threshold bin ----
  __threadfence();
  for (int b = 0; b < BATCH; ++b) {
    for (int i = tid; i < NBIN; i += 256) {
      uint32_t s = 0;
#pragma unroll
      for (int r = 0; r < NREP; ++r)
        s += __hip_atomic_load(&ws[16 + r * (BATCH * NBIN) + b * NBIN + i],
                               __ATOMIC_RELAXED, __HIP_MEMORY_SCOPE_AGENT);
      lh[i] = s;
    }
    __syncthreads();
    uint32_t s8 = 0;
#pragma unroll
    for (int k = 0; k < 8; ++k) s8 += lh[tid * 8 + k];
    ps[tid] = s8;
    __syncthreads();
    // inclusive suffix scan over 256 partials
    for (int off = 1; off < 256; off <<= 1) {
      uint32_t add = (tid + off < 256) ? ps[tid + off] : 0u;
      __syncthreads();
      ps[tid] += add;
      __syncthreads();
    }
    uint32_t run = ps[tid] - s8;   // count(bin >= 8*tid+8)
    for (int k = 7; k >= 0; --k) {
      uint32_t c = lh[tid * 8 + k];
      uint32_t nrun = run + c;
      if (nrun >= TOPK && run < TOPK)
        ws[b] = ((uint32_t)(tid * 8 + k)) << 21;
      run = nrun;
    }
    __syncthreads();
  }
}

__global__ void __launch_bounds__(256) k_compact(const float* __restrict__ s1,
                                                 const float* __restrict__ s2,
                                                 const float* __restrict__ s3,
                                                 uint32_t* ws) {
  __shared__ unsigned long long buf[BATCH][LCAP];
  __shared__ uint32_t cnt[BATCH], base[BATCH];
  if (threadIdx.x < BATCH) cnt[threadIdx.x] = 0;
  __syncthreads();
  const uint32_t T0 = ws[0], T1 = ws[1];
  unsigned long long* cand = (unsigned long long*)((char*)ws + 65600);
  for (int g = blockIdx.x * blockDim.x + threadIdx.x; g < TOT4;
       g += gridDim.x * blockDim.x) {
    int b, n0;
    float4 v = load_pair(g, s1, s2, s3, b, n0);
    uint32_t T = b ? T1 : T0;
#pragma unroll
    for (int h = 0; h < 2; ++h) {
      uint32_t key = fkey(h ? v.w : v.y);
      if (key >= T) {
        uint32_t n = (uint32_t)(n0 + h);
        unsigned long long pk = ((unsigned long long)key << 32) | (uint32_t)(~n);
        uint32_t p = atomicAdd(&cnt[b], 1u);
        if (p < LCAP) {
          buf[b][p] = pk;
        } else {  // overflow fallback (statistically never taken)
          uint32_t gp = atomicAdd(&ws[2 + b], 1u);
          if (gp < CANDCAP) cand[(unsigned)b * CANDCAP + gp] = pk;
        }
      }
    }
  }
  __syncthreads();
  if (threadIdx.x < BATCH) {
    uint32_t c = cnt[threadIdx.x];
    if (c > LCAP) c = LCAP;
    base[threadIdx.x] = atomicAdd(&ws[2 + threadIdx.x], c);
  }
  __syncthreads();
  for (int b = 0; b < BATCH; ++b) {
    uint32_t c = cnt[b];
    if (c > LCAP) c = LCAP;
    for (uint32_t i = threadIdx.x; i < c; i += blockDim.x) {
      uint32_t pos = base[b] + i;
      if (pos < CANDCAP) cand[(unsigned)b * CANDCAP + pos] = buf[b][i];
    }
  }
}

// Fused exact-rank (4-way-split brute force) + proposal decode/emit.
// Block = 256 threads = 64 candidates x 4 comparison splits.
__global__ void __launch_bounds__(256) k_rankemit(
    const float* __restrict__ b1, const float* __restrict__ b2,
    const float* __restrict__ b3, const float* __restrict__ anchors,
    const float* __restrict__ im_info, const uint32_t* ws,
    float* __restrict__ out) {
  __shared__ unsigned long long tile[512];
  __shared__ unsigned long long pkL[64];
  __shared__ uint32_t rk[64];
  const int b = blockIdx.y;
  const int tid = threadIdx.x;
  uint32_t cnt = ws[2 + b];
  if (cnt > CANDCAP) cnt = CANDCAP;
  const int cbase = blockIdx.x * 64;
  if (cbase >= (int)cnt) return;
  const unsigned long long* cand =
      (const unsigned long long*)((const char*)ws + 65600) + (unsigned)b * CANDCAP;

  const int lc = tid & 63;      // local candidate
  const int sp = tid >> 6;      // split 0..3
  const int ci = cbase + lc;
  unsigned long long mine = (ci < (int)cnt) ? cand[ci] : 0ULL;
  if (sp == 0) {
    rk[lc] = 0;
    pkL[lc] = mine;
  }
  __syncthreads();
  uint32_t r = 0;
  for (uint32_t t = 0; t < cnt; t += 512) {
    uint32_t lim = min(512u, cnt - t);
    for (uint32_t j = tid; j < lim; j += 256) tile[j] = cand[t + j];
    __syncthreads();
    if (ci < (int)cnt) {
      uint32_t j0 = sp * 128;
      uint32_t j1 = min(lim, j0 + 128u);
      for (uint32_t j = j0; j < j1; ++j) r += (tile[j] > mine) ? 1u : 0u;
    }
    __syncthreads();
  }
  if (r) atomicAdd(&rk[lc], r);
  __syncthreads();

  // ---- emit: 16 groups of 16 threads, 4 rounds ----
  const int g = tid >> 4, s = tid & 15;
  const float hmax = im_info[b * 3 + 0] - 1.0f;
  const float wmax = im_info[b * 3 + 1] - 1.0f;
  for (int q = 0; q < 4; ++q) {
    int l = g + q * 16;
    int i = cbase + l;
    if (i >= (int)cnt) continue;
    uint32_t rank = rk[l];
    if (rank >= TOPK) continue;
    unsigned long long p = pkL[l];
    uint32_t key = (uint32_t)(p >> 32);
    uint32_t n = ~(uint32_t)p;
    int j, a;
    const float* bb;
    long base;
    int td;
    if ((int)n < G1_END) {
      j = 0; a = (int)n; td = 16; bb = b1;
      base = ((long)b * A_CNT + a) * 64;
    } else if ((int)n < G2_END) {
      int m = (int)n - G1_END;
      j = m / A_CNT; a = m - j * A_CNT; td = 8; bb = b2;
      base = (((long)b * 9 + j) * A_CNT + a) * 32;
    } else {
      int m = (int)n - G2_END;
      j = m / A_CNT; a = m - j * A_CNT; td = 4; bb = b3;
      base = (((long)b * 13 + j) * A_CNT + a) * 16;
    }
    float x1, y1, x2, y2;
    if (s >= j && s < j + td) {
      const float4 an = *(const float4*)(anchors + (long)a * 4);
      const float4 d = *(const float4*)(bb + base + (long)(s - j) * 4);
      float aw = an.z - an.x + 1.0f, ah = an.w - an.y + 1.0f;
      float acx = an.x + 0.5f * aw, acy = an.y + 0.5f * ah;
      float pcx = d.x * aw + acx, pcy = d.y * ah + acy;
      float pw = expf(d.z) * aw, ph = expf(d.w) * ah;
      x1 = fminf(fmaxf(pcx - 0.5f * pw, 0.0f), wmax);
      y1 = fminf(fmaxf(pcy - 0.5f * ph, 0.0f), hmax);
      x2 = fminf(fmaxf(pcx + 0.5f * pw, 0.0f), wmax);
      y2 = fminf(fmaxf(pcy + 0.5f * ph, 0.0f), hmax);
    } else {
      x1 = 0.0f; y1 = 0.0f; x2 = 1.0f; y2 = 1.0f;
    }
    float* o = out + ((long)b * TOPK + rank) * 66;
    o[1 + 4 * s] = x1;
    o[2 + 4 * s] = y1;
    o[3 + 4 * s] = x2;
    o[4 + 4 * s] = y2;
    if (s == 0) {
      uint32_t sb = (key & 0x80000000u) ? (key ^ 0x80000000u) : ~key;
      o[0] = (float)b;
      o[65] = __uint_as_float(sb);
    }
  }
}

extern "C" void kernel_launch(void* const* d_in, const int* in_sizes, int n_in,
                              void* d_out, int out_size, void* d_ws, size_t ws_size,
                              hipStream_t stream) {
  const float* s1 = (const float*)d_in[0];
  const float* s2 = (const float*)d_in[1];
  const float* s3 = (const float*)d_in[2];
  const float* b1 = (const float*)d_in[3];
  const float* b2 = (const float*)d_in[4];
  const float* b3 = (const float*)d_in[5];
  const float* anchors = (const float*)d_in[6];
  const float* im_info = (const float*)d_in[7];
  uint32_t* ws = (uint32_t*)d_ws;
  float* out = (float*)d_out;

  k_init<<<(INIT_U4 + 255) / 256, 256, 0, stream>>>((uint4*)d_ws);
  k_histscan<<<HIST_BLOCKS, 256, 0, stream>>>(s1, s2, s3, ws);
  k_compact<<<256, 256, 0, stream>>>(s1, s2, s3, ws);
  dim3 rgrid(CANDCAP / 64, BATCH);
  k_rankemit<<<rgrid, 256, 0, stream>>>(b1, b2, b3, anchors, im_info, ws, out);
}

// Round 6
// 62.537 us; speedup vs baseline: 1.1960x; 1.1960x over previous
//
#include <hip/hip_runtime.h>
#include <stdint.h>

#define A_CNT 16320
#define N_TOT (23 * A_CNT)       // 375360 windowed anchors per batch
#define G1_END A_CNT             // group0: td=16, W=1
#define G2_END (10 * A_CNT)      // group1: td=8,  W=9
#define BATCH 2
#define TOPK 2000
#define NBIN 2048                // 11-bit histogram of key top bits
#define NREP 4                   // replicated global histograms
#define CANDCAP 4096
#define LCAP 256                 // per-block LDS candidate cap (per batch)
#define TOT4 375360              // total float4 loads (= BATCH*N_TOT/2)
#define INIT_U4 4100             // 65600 bytes / 16
#define HIST_BLOCKS 128
#define RCAND 128                // candidates per rank block
#define RSPLIT 2                 // comparison-domain splits per rank block

// ws layout:
//   u32[0..1]     T[2] threshold keys
//   u32[2..3]     gCandCnt[2]
//   u32[4]        done counter (last-block detection in k_histscan)
//   byte 64       hist replicas: NREP x [2][NBIN] u32 (64 KB) -- dead after scan
//   byte 1024     ranked[2][TOPK] u64 (32 KB) -- overlaps dead hist region;
//                 written by k_rank, read by k_emit
//   byte 65600    cand[2][CANDCAP] u64 (64 KB)
// total ~128 KB

__device__ __forceinline__ uint32_t fkey(float v) {
  uint32_t u = __float_as_uint(v);
  return (u & 0x80000000u) ? ~u : (u | 0x80000000u);
}

__global__ void k_init(uint4* ws4) {
  int g = blockIdx.x * blockDim.x + threadIdx.x;
  if (g < INIT_U4) ws4[g] = make_uint4(0u, 0u, 0u, 0u);
}

// g in [0, TOT4): one float4 = scores for anchors (n0, n0+1), batch b.
__device__ __forceinline__ float4 load_pair(int g, const float* __restrict__ s1,
                                            const float* __restrict__ s2,
                                            const float* __restrict__ s3,
                                            int& b, int& n0) {
  if (g < 16320) {                       // s1: [B][1][A][2]
    b = g / 8160;
    int w = g - b * 8160;
    n0 = 2 * w;
    return ((const float4*)s1)[g];
  } else if (g < 163200) {               // s2: [B][9][A][2]
    int h = g - 16320;
    b = h / 73440;
    int w = h - b * 73440;
    int j = w / 8160;
    int p = w - j * 8160;
    n0 = A_CNT + j * A_CNT + 2 * p;
    return ((const float4*)s2)[h];
  } else {                               // s3: [B][13][A][2]
    int h = g - 163200;
    b = h / 106080;
    int w = h - b * 106080;
    int j = w / 8160;
    int p = w - j * 8160;
    n0 = 10 * A_CNT + j * A_CNT + 2 * p;
    return ((const float4*)s3)[h];
  }
}

// Histogram + (in the last-arriving block) threshold scan, fused.
__global__ void __launch_bounds__(256) k_histscan(const float* __restrict__ s1,
                                                  const float* __restrict__ s2,
                                                  const float* __restrict__ s3,
                                                  uint32_t* ws) {
  __shared__ uint32_t lh[BATCH * NBIN];   // 16 KB
  __shared__ uint32_t ps[256];
  __shared__ uint32_t isLast;
  const int tid = threadIdx.x;
  for (int i = tid; i < BATCH * NBIN; i += 256) lh[i] = 0;
  __syncthreads();
  for (int g = blockIdx.x * 256 + tid; g < TOT4; g += gridDim.x * 256) {
    int b, n0;
    float4 v = load_pair(g, s1, s2, s3, b, n0);
    atomicAdd(&lh[b * NBIN + (fkey(v.y) >> 21)], 1u);
    atomicAdd(&lh[b * NBIN + (fkey(v.w) >> 21)], 1u);
  }
  __syncthreads();
  uint32_t* gh = ws + 16 + (blockIdx.x & (NREP - 1)) * (BATCH * NBIN);
  for (int i = tid; i < BATCH * NBIN; i += 256)
    if (lh[i]) atomicAdd(&gh[i], lh[i]);
  __threadfence();
  if (tid == 0) isLast = (atomicAdd(&ws[4], 1u) == (uint32_t)gridDim.x - 1u);
  __syncthreads();
  if (!isLast) return;

  // ---- last block: compute per-batch threshold bin ----
  __threadfence();
  for (int b = 0; b < BATCH; ++b) {
    for (int i = tid; i < NBIN; i += 256) {
      uint32_t s = 0;
#pragma unroll
      for (int r = 0; r < NREP; ++r)
        s += __hip_atomic_load(&ws[16 + r * (BATCH * NBIN) + b * NBIN + i],
                               __ATOMIC_RELAXED, __HIP_MEMORY_SCOPE_AGENT);
      lh[i] = s;
    }
    __syncthreads();
    uint32_t s8 = 0;
#pragma unroll
    for (int k = 0; k < 8; ++k) s8 += lh[tid * 8 + k];
    ps[tid] = s8;
    __syncthreads();
    // inclusive suffix scan over 256 partials
    for (int off = 1; off < 256; off <<= 1) {
      uint32_t add = (tid + off < 256) ? ps[tid + off] : 0u;
      __syncthreads();
      ps[tid] += add;
      __syncthreads();
    }
    uint32_t run = ps[tid] - s8;   // count(bin >= 8*tid+8)
    for (int k = 7; k >= 0; --k) {
      uint32_t c = lh[tid * 8 + k];
      uint32_t nrun = run + c;
      if (nrun >= TOPK && run < TOPK)
        ws[b] = ((uint32_t)(tid * 8 + k)) << 21;
      run = nrun;
    }
    __syncthreads();
  }
}

__global__ void __launch_bounds__(256) k_compact(const float* __restrict__ s1,
                                                 const float* __restrict__ s2,
                                                 const float* __restrict__ s3,
                                                 uint32_t* ws) {
  __shared__ unsigned long long buf[BATCH][LCAP];
  __shared__ uint32_t cnt[BATCH], base[BATCH];
  if (threadIdx.x < BATCH) cnt[threadIdx.x] = 0;
  __syncthreads();
  const uint32_t T0 = ws[0], T1 = ws[1];
  unsigned long long* cand = (unsigned long long*)((char*)ws + 65600);
  for (int g = blockIdx.x * blockDim.x + threadIdx.x; g < TOT4;
       g += gridDim.x * blockDim.x) {
    int b, n0;
    float4 v = load_pair(g, s1, s2, s3, b, n0);
    uint32_t T = b ? T1 : T0;
#pragma unroll
    for (int h = 0; h < 2; ++h) {
      uint32_t key = fkey(h ? v.w : v.y);
      if (key >= T) {
        uint32_t n = (uint32_t)(n0 + h);
        unsigned long long pk = ((unsigned long long)key << 32) | (uint32_t)(~n);
        uint32_t p = atomicAdd(&cnt[b], 1u);
        if (p < LCAP) {
          buf[b][p] = pk;
        } else {  // overflow fallback (statistically never taken)
          uint32_t gp = atomicAdd(&ws[2 + b], 1u);
          if (gp < CANDCAP) cand[(unsigned)b * CANDCAP + gp] = pk;
        }
      }
    }
  }
  __syncthreads();
  if (threadIdx.x < BATCH) {
    uint32_t c = cnt[threadIdx.x];
    if (c > LCAP) c = LCAP;
    base[threadIdx.x] = atomicAdd(&ws[2 + threadIdx.x], c);
  }
  __syncthreads();
  for (int b = 0; b < BATCH; ++b) {
    uint32_t c = cnt[b];
    if (c > LCAP) c = LCAP;
    for (uint32_t i = threadIdx.x; i < c; i += blockDim.x) {
      uint32_t pos = base[b] + i;
      if (pos < CANDCAP) cand[(unsigned)b * CANDCAP + pos] = buf[b][i];
    }
  }
}

// Exact stable descending rank, brute force. 256 threads = 128 candidates x
// 2 splits. 8-wide manual unroll keeps 8 independent ds_read_b64 in flight.
__global__ void __launch_bounds__(256) k_rank(uint32_t* ws) {
  __shared__ unsigned long long tile[1024];
  __shared__ uint32_t rk[RCAND];
  const int b = blockIdx.y;
  const int tid = threadIdx.x;
  uint32_t cnt = ws[2 + b];
  if (cnt > CANDCAP) cnt = CANDCAP;
  const int cbase = blockIdx.x * RCAND;
  if (cbase >= (int)cnt) return;
  const unsigned long long* cand =
      (const unsigned long long*)((const char*)ws + 65600) + (unsigned)b * CANDCAP;
  unsigned long long* ranked =
      (unsigned long long*)((char*)ws + 1024) + (unsigned)b * TOPK;

  const int lc = tid & (RCAND - 1);
  const int sp = tid >> 7;             // 0..RSPLIT-1
  const int ci = cbase + lc;
  unsigned long long mine = (ci < (int)cnt) ? cand[ci] : 0ULL;
  if (sp == 0) rk[lc] = 0;
  __syncthreads();

  uint32_t r = 0;
  for (uint32_t t = 0; t < cnt; t += 1024) {
    uint32_t lim = min(1024u, cnt - t);
    for (uint32_t j = tid; j < lim; j += 256) tile[j] = cand[t + j];
    __syncthreads();
    uint32_t j0 = sp * 512;
    uint32_t j1 = min(lim, j0 + 512u);
    uint32_t j = j0;
    for (; j + 8 <= j1; j += 8) {
      unsigned long long t0 = tile[j + 0], t1 = tile[j + 1];
      unsigned long long t2 = tile[j + 2], t3 = tile[j + 3];
      unsigned long long t4 = tile[j + 4], t5 = tile[j + 5];
      unsigned long long t6 = tile[j + 6], t7 = tile[j + 7];
      r += (t0 > mine) ? 1u : 0u;
      r += (t1 > mine) ? 1u : 0u;
      r += (t2 > mine) ? 1u : 0u;
      r += (t3 > mine) ? 1u : 0u;
      r += (t4 > mine) ? 1u : 0u;
      r += (t5 > mine) ? 1u : 0u;
      r += (t6 > mine) ? 1u : 0u;
      r += (t7 > mine) ? 1u : 0u;
    }
    for (; j < j1; ++j) r += (tile[j] > mine) ? 1u : 0u;
    __syncthreads();
  }
  if (r) atomicAdd(&rk[lc], r);
  __syncthreads();
  if (sp == 0 && ci < (int)cnt) {
    uint32_t rank = rk[lc];
    if (rank < TOPK) ranked[rank] = mine;
  }
}

__global__ void k_emit(const float* __restrict__ b1, const float* __restrict__ b2,
                       const float* __restrict__ b3, const float* __restrict__ anchors,
                       const float* __restrict__ im_info, const uint32_t* ws,
                       float* __restrict__ out) {
  int gid = blockIdx.x * blockDim.x + threadIdx.x;
  int e = gid >> 4;
  int s = gid & 15;
  if (e >= BATCH * TOPK) return;
  int b = e / TOPK;
  int r = e - b * TOPK;
  const unsigned long long* ranked =
      (const unsigned long long*)((const char*)ws + 1024);
  unsigned long long p = ranked[(unsigned)b * TOPK + r];
  uint32_t key = (uint32_t)(p >> 32);
  uint32_t n = ~(uint32_t)p;

  int j, a, td;
  const float* bb;
  long base;
  if ((int)n < G1_END) {
    j = 0; a = (int)n; td = 16; bb = b1;
    base = ((long)b * A_CNT + a) * 64;
  } else if ((int)n < G2_END) {
    int m = (int)n - G1_END;
    j = m / A_CNT; a = m - j * A_CNT; td = 8; bb = b2;
    base = (((long)b * 9 + j) * A_CNT + a) * 32;
  } else {
    int m = (int)n - G2_END;
    j = m / A_CNT; a = m - j * A_CNT; td = 4; bb = b3;
    base = (((long)b * 13 + j) * A_CNT + a) * 16;
  }

  float x1, y1, x2, y2;
  if (s >= j && s < j + td) {
    const float4 an = *(const float4*)(anchors + (long)a * 4);
    const float4 d = *(const float4*)(bb + base + (long)(s - j) * 4);
    float aw = an.z - an.x + 1.0f, ah = an.w - an.y + 1.0f;
    float acx = an.x + 0.5f * aw, acy = an.y + 0.5f * ah;
    float pcx = d.x * aw + acx, pcy = d.y * ah + acy;
    float pw = expf(d.z) * aw, ph = expf(d.w) * ah;
    float hmax = im_info[b * 3 + 0] - 1.0f;
    float wmax = im_info[b * 3 + 1] - 1.0f;
    x1 = fminf(fmaxf(pcx - 0.5f * pw, 0.0f), wmax);
    y1 = fminf(fmaxf(pcy - 0.5f * ph, 0.0f), hmax);
    x2 = fminf(fmaxf(pcx + 0.5f * pw, 0.0f), wmax);
    y2 = fminf(fmaxf(pcy + 0.5f * ph, 0.0f), hmax);
  } else {
    x1 = 0.0f; y1 = 0.0f; x2 = 1.0f; y2 = 1.0f;
  }
  float* o = out + (long)e * 66;
  o[1 + 4 * s] = x1;
  o[2 + 4 * s] = y1;
  o[3 + 4 * s] = x2;
  o[4 + 4 * s] = y2;
  if (s == 0) {
    uint32_t sb = (key & 0x80000000u) ? (key ^ 0x80000000u) : ~key;
    o[0] = (float)b;
    o[65] = __uint_as_float(sb);
  }
}

extern "C" void kernel_launch(void* const* d_in, const int* in_sizes, int n_in,
                              void* d_out, int out_size, void* d_ws, size_t ws_size,
                              hipStream_t stream) {
  const float* s1 = (const float*)d_in[0];
  const float* s2 = (const float*)d_in[1];
  const float* s3 = (const float*)d_in[2];
  const float* b1 = (const float*)d_in[3];
  const float* b2 = (const float*)d_in[4];
  const float* b3 = (const float*)d_in[5];
  const float* anchors = (const float*)d_in[6];
  const float* im_info = (const float*)d_in[7];
  uint32_t* ws = (uint32_t*)d_ws;
  float* out = (float*)d_out;

  k_init<<<(INIT_U4 + 255) / 256, 256, 0, stream>>>((uint4*)d_ws);
  k_histscan<<<HIST_BLOCKS, 256, 0, stream>>>(s1, s2, s3, ws);
  k_compact<<<256, 256, 0, stream>>>(s1, s2, s3, ws);
  dim3 rgrid(CANDCAP / RCAND, BATCH);
  k_rank<<<rgrid, 256, 0, stream>>>(ws);
  int threads = BATCH * TOPK * 16;
  k_emit<<<(threads + 255) / 256, 256, 0, stream>>>(b1, b2, b3, anchors, im_info,
                                                    ws, out);
}